// Round 15
// baseline (199.724 us; speedup 1.0000x reference)
//
#include <hip/hip_runtime.h>
#include <hip/hip_bf16.h>
#include <math.h>

#define DEV __device__ __forceinline__

typedef short bf16x8 __attribute__((ext_vector_type(8)));
typedef short bf16x4 __attribute__((ext_vector_type(4)));
typedef float f32x4 __attribute__((ext_vector_type(4)));

static constexpr int D  = 1024;
static constexpr int H  = 16;
static constexpr int HD = 64;
static constexpr int DS = 64;
static constexpr int B  = 2;
static constexpr int L  = 2048;
static constexpr int M  = B * L;   // 4096

// softmax scale * log2(e), folded into q at projection time (exp2-based
// softmax, no max subtraction: scores bounded far below exp2 overflow;
// masked scores (-1e30) give exp2 -> 0 exactly).
static constexpr float QSCALE = 0.18033688011112042f; // 0.125 * log2(e)

DEV unsigned short f2bf(float f) {
  union { float f; unsigned u; } x; x.f = f;
  unsigned r = (x.u + 0x7FFFu + ((x.u >> 16) & 1u)) >> 16;
  return (unsigned short)r;
}

DEV unsigned pack2bf(float a, float b) {
  return (unsigned)f2bf(a) | ((unsigned)f2bf(b) << 16);
}

// truncation pack (P only: truncation bias cancels between Sum(p*v) and Sum(p))
// single v_perm_b32: bytes [ua.b2, ua.b3, ub.b2, ub.b3]
DEV unsigned pack2bf_trunc(float a, float b) {
  union { float f; unsigned u; } ua{a}, ub{b};
  return __builtin_amdgcn_perm(ub.u, ua.u, 0x07060302u);
}

// async global->LDS, 16B per lane; LDS dest = wave-uniform base + 16*lane.
DEV void gload_lds16(const void* g, void* l) {
  __builtin_amdgcn_global_load_lds(
      (const __attribute__((address_space(1))) unsigned int*)g,
      (__attribute__((address_space(3))) unsigned int*)l, 16, 0, 0);
}

// ---------------- merged preprocessing ----------------
// blocks [0,1024): W transpose+bf16 (vectorized: float4 reads, ushort4
// transposed stores); [1024,3072): x->bf16; [3072,3088): sq/sk
__global__ __launch_bounds__(256) void prep_kernel(
    const float* __restrict__ Wq, const float* __restrict__ Wk,
    const float* __restrict__ Wv, const float* __restrict__ Wo,
    const float* __restrict__ x, const float* __restrict__ subj,
    const float* __restrict__ Wsq, const float* __restrict__ bsq,
    const float* __restrict__ Wsk, const float* __restrict__ bsk,
    unsigned short* __restrict__ WT4, unsigned short* __restrict__ xb,
    float* __restrict__ sq, float* __restrict__ sk) {
  __shared__ float tile[64][65];
  const int blk = blockIdx.x, t = threadIdx.x;
  if (blk < 1024) {
    const int z = blk >> 8, idx = blk & 255;
    const float* W = z == 0 ? Wq : z == 1 ? Wk : z == 2 ? Wv : Wo;
    unsigned short* dst = WT4 + (size_t)z * D * D;
    const int n0 = (idx & 15) * 64, k0 = (idx >> 4) * 64;
    const int c4 = (t & 15) * 4;   // 4-col group
    const int r16 = t >> 4;        // 0..15
#pragma unroll
    for (int rr = 0; rr < 4; ++rr) {
      int row = r16 + rr * 16;
      float4 v = *(const float4*)&W[(size_t)(k0 + row) * D + n0 + c4];
      tile[row][c4 + 0] = v.x;
      tile[row][c4 + 1] = v.y;
      tile[row][c4 + 2] = v.z;
      tile[row][c4 + 3] = v.w;
    }
    __syncthreads();
#pragma unroll
    for (int rr = 0; rr < 4; ++rr) {
      int nrow = r16 + rr * 16;
      ushort4 u;
      u.x = f2bf(tile[c4 + 0][nrow]);
      u.y = f2bf(tile[c4 + 1][nrow]);
      u.z = f2bf(tile[c4 + 2][nrow]);
      u.w = f2bf(tile[c4 + 3][nrow]);
      *(ushort4*)&dst[(size_t)(n0 + nrow) * D + k0 + c4] = u;
    }
  } else if (blk < 3072) {
    size_t g = (size_t)(blk - 1024) * 256 + t;
    const float4* xf = (const float4*)x;
    float4 a = xf[2 * g], b = xf[2 * g + 1];
    union { unsigned short s[8]; uint4 v; } o;
    o.s[0] = f2bf(a.x); o.s[1] = f2bf(a.y); o.s[2] = f2bf(a.z); o.s[3] = f2bf(a.w);
    o.s[4] = f2bf(b.x); o.s[5] = f2bf(b.y); o.s[6] = f2bf(b.z); o.s[7] = f2bf(b.w);
    ((uint4*)xb)[g] = o.v;
  } else {
    int g = (blk - 3072) * 256 + t;  // [0, 4096)
    int ty = g >> 11, b = (g >> 10) & 1, n = g & 1023;
    const float* W = ty ? Wsk : Wsq;
    const float* bias = ty ? bsk : bsq;
    float s = bias[n];
#pragma unroll 8
    for (int d = 0; d < DS; ++d) s += subj[b * DS + d] * W[d * D + n];
    (ty ? sk : sq)[b * D + n] = s;
  }
}

// ---------------- fused QKV projection GEMM (z-FUSED, BK=64 dbuf) -------
// One block computes q, k AND v for a 128(m) x 64(n=one head) tile: the
// shared A-operand (xb) is staged ONCE per K-step for 48 MFMAs (3 z x 16).
// Grid 512 = exactly 1 dispatch round. Per buf: As 16 KB + 3x Bs 8 KB =
// 40 KB; dbuf 80 KB -> 2 blocks/CU. 2D XCD chunk (8m x 8n per XCD).
// Three sequential epilogues (q, k: bias+coalesced; v: fused transpose).
__global__ __launch_bounds__(256) void proj_kernel(
    const unsigned short* __restrict__ xb, const unsigned short* __restrict__ WT3,
    const float* __restrict__ sq, const float* __restrict__ sk,
    unsigned short* __restrict__ qk, unsigned short* __restrict__ vT) {
  __shared__ __align__(16) unsigned short smem[40960];  // 80 KB: 2 bufs x 40 KB
  const int lin = blockIdx.x + 8 * blockIdx.y;     // 0..511
  const int x8 = lin & 7, c = lin >> 3;            // XCD, chunk idx 0..63
  const int mt = (x8 & 3) * 8 + (c >> 3);          // m-tile 0..31
  const int nt = (x8 >> 2) * 8 + (c & 7);          // n-tile (= head) 0..15
  const int m0 = mt * 128, n0 = nt * 64;
  const int t = threadIdx.x, l = t & 63, w = t >> 6;
  const int lm = l & 15, lq = l >> 4;
  const int srow8 = t >> 3;
  const int fsw = ((t & 7) ^ ((t >> 3) & 7)) * 8;
  const int swm = lm & 7;

  auto stage = [&](int kt, int bsel) {
    const int kb = kt * 64;
    unsigned short* As = smem + bsel * 20480;
    unsigned short* Bs = As + 8192;
#pragma unroll
    for (int cc = 0; cc < 4; ++cc)
      gload_lds16(&xb[(size_t)(m0 + 32 * cc + srow8) * D + kb + fsw],
                  &As[(32 * cc + 8 * w) * 64]);
#pragma unroll
    for (int z = 0; z < 3; ++z)
#pragma unroll
      for (int cc = 0; cc < 2; ++cc)
        gload_lds16(&WT3[(size_t)z * D * D + (size_t)(n0 + 32 * cc + srow8) * D + kb + fsw],
                    &Bs[z * 4096 + (32 * cc + 8 * w) * 64]);
  };

  f32x4 acc[3][2][4] = {};
  stage(0, 0);
  __syncthreads();
  for (int kt = 0; kt < D / 64; ++kt) {
    const int cur = kt & 1;
    if (kt + 1 < D / 64) stage(kt + 1, cur ^ 1);
    const unsigned short* As = smem + cur * 20480;
    const unsigned short* Bs = As + 8192;
#pragma unroll
    for (int kk = 0; kk < 2; ++kk) {
      bf16x8 af[2];
#pragma unroll
      for (int i = 0; i < 2; ++i)
        af[i] = *(const bf16x8*)&As[(32 * w + 16 * i + lm) * 64 + ((kk * 4 + lq) ^ swm) * 8];
#pragma unroll
      for (int z = 0; z < 3; ++z)
#pragma unroll
        for (int j = 0; j < 4; ++j) {
          bf16x8 bfj = *(const bf16x8*)&Bs[z * 4096 + (16 * j + lm) * 64 + ((kk * 4 + lq) ^ swm) * 8];
#pragma unroll
          for (int i = 0; i < 2; ++i)
            acc[z][i][j] = __builtin_amdgcn_mfma_f32_16x16x32_bf16(af[i], bfj, acc[z][i][j], 0, 0, 0);
        }
    }
    __syncthreads();  // vmcnt(0): prefetch (issued pre-compute) has landed
  }

  const int bb = m0 >> 11;          // batch
  const int l0 = m0 & (L - 1);      // seq offset
  const int h0 = nt;                // head (n0 = 64*nt)

  // ---- q/k epilogues: bias + QSCALE, stride-72 staging, coalesced stores
#pragma unroll
  for (int z = 0; z < 2; ++z) {
    const float* bias = z == 0 ? sq : sk;
    const float post = z == 0 ? QSCALE : 1.0f;
    unsigned short* dst = qk + (size_t)z * M * D;
#pragma unroll
    for (int i = 0; i < 2; ++i)
#pragma unroll
      for (int j = 0; j < 4; ++j)
#pragma unroll
        for (int r = 0; r < 4; ++r) {
          int rr = 32 * w + 16 * i + 4 * lq + r;
          int cc = 16 * j + lm;
          float v = (acc[z][i][j][r] + bias[bb * D + n0 + cc]) * post;
          smem[rr * 72 + cc] = f2bf(v);
        }
    __syncthreads();
    const int row = t >> 1, half = t & 1;
    size_t dbase = ((size_t)(bb * H + h0) * L + l0 + row) * HD + half * 32;
#pragma unroll
    for (int cq = 0; cq < 4; ++cq) {
      uint4 u = *(const uint4*)&smem[row * 72 + half * 32 + cq * 8];
      *(uint4*)&dst[dbase + cq * 8] = u;
    }
    __syncthreads();   // all reads done before next epilogue overwrites
  }

  // ---- v epilogue: transpose through smem (stride 136) -> vT[bh][hd][l]
#pragma unroll
  for (int i = 0; i < 2; ++i)
#pragma unroll
    for (int j = 0; j < 4; ++j) {
      int cr = 16 * j + lm;                 // hd 0..63
      int rr = 32 * w + 16 * i + 4 * lq;    // l-row 0..124
      uint2 u;
      u.x = pack2bf(acc[2][i][j][0], acc[2][i][j][1]);
      u.y = pack2bf(acc[2][i][j][2], acc[2][i][j][3]);
      *(uint2*)&smem[cr * 136 + rr] = u;
    }
  __syncthreads();
  {
    const int cr = t >> 2, quarter = t & 3;   // hd row, 32-el quarter
    size_t dbase = ((size_t)(bb * H + h0) * HD + cr) * L + l0 + quarter * 32;
#pragma unroll
    for (int cq = 0; cq < 4; ++cq) {
      uint4 u = *(const uint4*)&smem[cr * 136 + quarter * 32 + cq * 8];
      *(uint4*)&vT[dbase + cq * 8] = u;
    }
  }
}

// ---------------- flash attention (64-row q-tiles, 64-key tiles) -------
// Grid 1024 (8 XCDs x 128 chunks; 32 same-bh blocks per XCD -> K/V 512 KB
// L2-resident). Block 256 = 4 waves; wave w owns q-rows q0+16w..+15 and
// ALL 64 keys of each tile (2 K=32 groups; same remap/exp2/pack math as
// before with the i-dimension dropped). 40 KB LDS -> 4 blocks/CU capacity
// (the r14 80 KB config fit 160 KB exactly -- measured occupancy 31% vs
// 50% theoretical suggests residency was 1 block/CU; this config cannot
// be edge-of-pool fragile) and grid 1024 = 4/CU removes tail rounds.
// NO pair-combine epilogue: each wave owns its rows fully; rlq = 1/ot1[r]
// is lane-local (ones-column MFMA row-sums), zero shuffles.
__global__ __launch_bounds__(256) void attn_kernel(
    const unsigned short* __restrict__ q_hm, const unsigned short* __restrict__ k_hm,
    const unsigned short* __restrict__ vT, const unsigned char* __restrict__ mask,
    unsigned short* __restrict__ ctx) {
  __shared__ __align__(16) unsigned short smem[20480];  // 40 KB pool
  unsigned short* Qs  = smem;            // 64x64   (8 KB)
  unsigned short* Ksb = smem + 4096;     // 2x64x64 (16 KB) [buf][key][feat]
  unsigned short* Vtb = smem + 12288;    // 2x64x64 (16 KB) [buf][feat][key]
  const int bx = blockIdx.x;
  const int rest = bx >> 3;                       // 0..127
  const int bhid = (bx & 7) + 8 * (rest >> 5);    // 0..31
  const int q0 = (rest & 31) * 64;
  const int h = bhid & 15, b = bhid >> 4;
  const size_t bh = (size_t)(b * H + h);
  const unsigned short* qp = q_hm + bh * L * HD;
  const unsigned short* kp = k_hm + bh * L * HD;
  const unsigned short* vp = vT + bh * HD * L;
  const int t = threadIdx.x, l = t & 63, w = t >> 6;   // w 0..3
  const int lm = l & 15, lq = l >> 4;
  const int fsw = ((t & 7) ^ ((t >> 3) & 7)) * 8;  // 8-chunk swizzle (64-wide rows)
  const int swm = lm & 7;
  const int srow8 = t >> 3;                        // 0..31
  // K=32 A-layout key-row remap (keys for C-row c=4lq+r: 8lq+4(lq&1)+r)
  const int krow0 = 8 * (lm >> 2) + 4 * ((lm >> 2) & 1) + (lm & 3);
  const int ks0 = krow0 & 7;
  const int krow1 = krow0 ^ 4;
  const int ks1 = ks0 ^ 4;
  const bf16x8 vones = {(short)0x3F80, (short)0x3F80, (short)0x3F80, (short)0x3F80,
                        (short)0x3F80, (short)0x3F80, (short)0x3F80, (short)0x3F80};

  // prologue: stage Q + first K/V tile (2 DMAs each per thread)
#pragma unroll
  for (int c = 0; c < 2; ++c) {
    gload_lds16(&qp[(size_t)(q0 + 32 * c + srow8) * HD + fsw], &Qs[(32 * c + 8 * w) * 64]);
    gload_lds16(&kp[(size_t)(32 * c + srow8) * HD + fsw], &Ksb[(32 * c + 8 * w) * 64]);
    gload_lds16(&vp[(size_t)(32 * c + srow8) * L + fsw], &Vtb[(32 * c + 8 * w) * 64]);
  }
  __syncthreads();
  bf16x8 qf[2];
#pragma unroll
  for (int kk = 0; kk < 2; ++kk)
    qf[kk] = *(const bf16x8*)&Qs[(16 * w + lm) * 64 + ((kk * 4 + lq) ^ swm) * 8];

  f32x4 ot[4] = {};   // O[qrow=16w+4lq+r][feat=16jf+lm]
  f32x4 ot1 = {};     // row-sums (ones-column), lane rows 4lq+r

  for (int kt = 0; kt < L / 64; ++kt) {
    const int cur = kt & 1;
    const unsigned short* Kc = Ksb + cur * 4096;
    const unsigned short* Vc = Vtb + cur * 4096;
    // mask bytes FIRST (oldest vmcnt entries)
    unsigned char mby = mask[b * L + kt * 64 + l];
    if (kt + 1 < L / 64) {
      const int nk0 = (kt + 1) * 64;
      unsigned short* Kd = Ksb + (cur ^ 1) * 4096;
      unsigned short* Vd = Vtb + (cur ^ 1) * 4096;
#pragma unroll
      for (int c = 0; c < 2; ++c) {
        gload_lds16(&kp[(size_t)(nk0 + 32 * c + srow8) * HD + fsw], &Kd[(32 * c + 8 * w) * 64]);
        gload_lds16(&vp[(size_t)(32 * c + srow8) * L + nk0 + fsw], &Vd[(32 * c + 8 * w) * 64]);
      }
    }
    unsigned long long mb = __ballot(mby != 0);

#pragma unroll
    for (int g = 0; g < 2; ++g) {
      const unsigned short* Kg = Kc + 2048 * g;    // 32-key group
      bf16x8 ka0 = *(const bf16x8*)&Kg[krow0 * 64 + ((0 + lq) ^ ks0) * 8];
      bf16x8 ka1 = *(const bf16x8*)&Kg[krow0 * 64 + ((4 + lq) ^ ks0) * 8];
      bf16x8 kb0 = *(const bf16x8*)&Kg[krow1 * 64 + ((0 + lq) ^ ks1) * 8];
      bf16x8 kb1 = *(const bf16x8*)&Kg[krow1 * 64 + ((4 + lq) ^ ks1) * 8];
      f32x4 stA = {}, stB = {};
      __builtin_amdgcn_s_setprio(1);
      stA = __builtin_amdgcn_mfma_f32_16x16x32_bf16(ka0, qf[0], stA, 0, 0, 0);
      stA = __builtin_amdgcn_mfma_f32_16x16x32_bf16(ka1, qf[1], stA, 0, 0, 0);
      stB = __builtin_amdgcn_mfma_f32_16x16x32_bf16(kb0, qf[0], stB, 0, 0, 0);
      stB = __builtin_amdgcn_mfma_f32_16x16x32_bf16(kb1, qf[1], stB, 0, 0, 0);
      __builtin_amdgcn_s_setprio(0);
      if (mb) {  // wave-uniform; all-false mask skips this
        const int shA = 32 * g + 8 * lq + 4 * (lq & 1);
        unsigned bitsA = (unsigned)(mb >> shA);
        unsigned bitsB = (unsigned)(mb >> (shA ^ 4));
#pragma unroll
        for (int r = 0; r < 4; ++r) {
          if ((bitsA >> r) & 1u) stA[r] = -1e30f;
          if ((bitsB >> r) & 1u) stB[r] = -1e30f;
        }
      }
      // p = exp2(s); build K=32 A-fragment (lq parity selects quad order)
      union { uint4 q; bf16x8 v; } pa;
      const bool sw = (lq & 1) != 0;
      float eA[4], eB[4];
#pragma unroll
      for (int r = 0; r < 4; ++r) {
        eA[r] = __builtin_amdgcn_exp2f(stA[r]);
        eB[r] = __builtin_amdgcn_exp2f(stB[r]);
      }
      unsigned a01 = pack2bf_trunc(eA[0], eA[1]);
      unsigned a23 = pack2bf_trunc(eA[2], eA[3]);
      unsigned b01 = pack2bf_trunc(eB[0], eB[1]);
      unsigned b23 = pack2bf_trunc(eB[2], eB[3]);
      pa.q.x = sw ? b01 : a01;
      pa.q.y = sw ? b23 : a23;
      pa.q.z = sw ? a01 : b01;
      pa.q.w = sw ? a23 : b23;
      // O += P@V (b128 V^T reads, K=32 MFMA); ones-column MFMA -> row sums
      const int kc = 4 * g + lq;                   // 8-key chunk in 64-key row
      const int slot = kc ^ swm;
      __builtin_amdgcn_s_setprio(1);
#pragma unroll
      for (int jf = 0; jf < 4; ++jf) {
        bf16x8 vb = *(const bf16x8*)&Vc[(16 * jf + lm) * 64 + slot * 8];
        ot[jf] = __builtin_amdgcn_mfma_f32_16x16x32_bf16(pa.v, vb, ot[jf], 0, 0, 0);
      }
      ot1 = __builtin_amdgcn_mfma_f32_16x16x32_bf16(pa.v, vones, ot1, 0, 0, 0);
      __builtin_amdgcn_s_setprio(0);
    }
    __syncthreads();
  }

  // ---- epilogue: lane-local normalize, stride-72 staging, coalesced ----
  float rlq[4];
#pragma unroll
  for (int r = 0; r < 4; ++r) rlq[r] = 1.0f / ot1[r];
  unsigned short* Es = smem;   // 64 rows x stride 72 = 9.2 KB (Q/K0 dead)
#pragma unroll
  for (int jf = 0; jf < 4; ++jf)
#pragma unroll
    for (int r = 0; r < 4; ++r)
      Es[(16 * w + 4 * lq + r) * 72 + 16 * jf + lm] = f2bf(ot[jf][r] * rlq[r]);
  __syncthreads();
  {
    const int row = t >> 2, q4 = t & 3;
    size_t obase = ((size_t)(b * L + q0 + row)) * D + h * HD + q4 * 16;
#pragma unroll
    for (int c = 0; c < 2; ++c) {
      uint4 u = *(const uint4*)&Es[row * 72 + q4 * 16 + c * 8];
      *(uint4*)&ctx[obase + c * 8] = u;
    }
  }
}

// ---------------- output projection GEMM (BK=64, 2-phase dbuf) ----------
// out = ctx@Wo + bo. XCD-chunked block swizzle (bijective: 512 = 8 x 64)
// + 2-phase gload_lds prefetch (grid 512 = exactly 2 blocks/CU).
__global__ __launch_bounds__(256) void outgemm_kernel(
    const unsigned short* __restrict__ ctx, const unsigned short* __restrict__ WoT,
    const float* __restrict__ bo, float* __restrict__ out) {
  __shared__ __align__(16) unsigned short smem[24576];  // 48 KB: 2x(As+Bs)
  const int lin = blockIdx.x + 8 * blockIdx.y;
  const int nlin = (lin & 7) * 64 + (lin >> 3);   // XCD chunk remap
  const int m0 = (nlin >> 3) * 64, n0 = (nlin & 7) * 128;
  const int t = threadIdx.x, l = t & 63, w = t >> 6;
  const int wm = w >> 1, wn = w & 1;
  const int lm = l & 15, lq = l >> 4;
  const int srow8 = t >> 3;
  const int fsw = ((t & 7) ^ ((t >> 3) & 7)) * 8;
  const int swm = lm & 7;

  auto stage = [&](int kt, int bsel) {
    const int kb = kt * 64;
    unsigned short* As = smem + bsel * 12288;
    unsigned short* Bs = As + 4096;
#pragma unroll
    for (int c = 0; c < 2; ++c)
      gload_lds16(&ctx[(size_t)(m0 + 32 * c + srow8) * D + kb + fsw],
                  &As[(32 * c + 8 * w) * 64]);
#pragma unroll
    for (int c = 0; c < 4; ++c)
      gload_lds16(&WoT[(size_t)(n0 + 32 * c + srow8) * D + kb + fsw],
                  &Bs[(32 * c + 8 * w) * 64]);
  };

  f32x4 acc[2][4] = {};
  stage(0, 0);
  __syncthreads();
  for (int kt = 0; kt < D / 64; ++kt) {
    const int cur = kt & 1;
    if (kt + 1 < D / 64) stage(kt + 1, cur ^ 1);
    const unsigned short* As = smem + cur * 12288;
    const unsigned short* Bs = As + 4096;
#pragma unroll
    for (int kk = 0; kk < 2; ++kk) {
      bf16x8 af[2], bf[4];
#pragma unroll
      for (int i = 0; i < 2; ++i)
        af[i] = *(const bf16x8*)&As[(32 * wm + 16 * i + lm) * 64 + ((kk * 4 + lq) ^ swm) * 8];
#pragma unroll
      for (int j = 0; j < 4; ++j)
        bf[j] = *(const bf16x8*)&Bs[(64 * wn + 16 * j + lm) * 64 + ((kk * 4 + lq) ^ swm) * 8];
#pragma unroll
      for (int i = 0; i < 2; ++i)
#pragma unroll
        for (int j = 0; j < 4; ++j)
          acc[i][j] = __builtin_amdgcn_mfma_f32_16x16x32_bf16(af[i], bf[j], acc[i][j], 0, 0, 0);
    }
    __syncthreads();
  }
#pragma unroll
  for (int i = 0; i < 2; ++i)
#pragma unroll
    for (int j = 0; j < 4; ++j)
#pragma unroll
      for (int r = 0; r < 4; ++r) {
        int grow = m0 + 32 * wm + 16 * i + lq * 4 + r;
        int gcol = n0 + 64 * wn + 16 * j + lm;
        out[(size_t)grow * D + gcol] = acc[i][j][r] + bo[gcol];
      }
}

extern "C" void kernel_launch(void* const* d_in, const int* in_sizes, int n_in,
                              void* d_out, int out_size, void* d_ws, size_t ws_size,
                              hipStream_t stream) {
  const float* x    = (const float*)d_in[0];
  const float* subj = (const float*)d_in[1];
  const unsigned char* mask = (const unsigned char*)d_in[2];
  const float* Wq = (const float*)d_in[3];
  const float* Wk = (const float*)d_in[4];
  const float* Wv = (const float*)d_in[5];
  const float* Wo = (const float*)d_in[6];
  const float* bo = (const float*)d_in[7];
  const float* Wsq = (const float*)d_in[8];
  const float* bsq = (const float*)d_in[9];
  const float* Wsk = (const float*)d_in[10];
  const float* bsk = (const float*)d_in[11];
  float* out = (float*)d_out;
  char* ws = (char*)d_ws;

  // workspace layout (bytes)
  unsigned short* xb  = (unsigned short*)(ws);                    // 8 MB
  unsigned short* WT4 = (unsigned short*)(ws + (8ull  << 20));    // 8 MB
  unsigned short* qk  = (unsigned short*)(ws + (16ull << 20));    // 16 MB (q,k)
  unsigned short* ctx = (unsigned short*)(ws + (32ull << 20));    // 8 MB
  unsigned short* vT  = (unsigned short*)(ws + (40ull << 20));    // 8 MB
  float* sq = (float*)(ws + (48ull << 20));                       // 8 KB
  float* sk = sq + B * D;

  hipLaunchKernelGGL(prep_kernel, dim3(3088), dim3(256), 0, stream,
                     Wq, Wk, Wv, Wo, x, subj, Wsq, bsq, Wsk, bsk, WT4, xb, sq, sk);
  hipLaunchKernelGGL(proj_kernel, dim3(8, 64, 1), dim3(256), 0, stream,
                     xb, WT4, sq, sk, qk, vT);
  hipLaunchKernelGGL(attn_kernel, dim3(1024), dim3(256), 0, stream,
                     qk, qk + (size_t)M * D, vT, mask, ctx);
  hipLaunchKernelGGL(outgemm_kernel, dim3(8, 64, 1), dim3(256), 0, stream, ctx,
                     WT4 + 3ull * D * D, bo, out);
}

// Round 16
// 188.408 us; speedup vs baseline: 1.0601x; 1.0601x over previous
//
#include <hip/hip_runtime.h>
#include <hip/hip_bf16.h>
#include <math.h>

#define DEV __device__ __forceinline__

typedef short bf16x8 __attribute__((ext_vector_type(8)));
typedef short bf16x4 __attribute__((ext_vector_type(4)));
typedef float f32x4 __attribute__((ext_vector_type(4)));

static constexpr int D  = 1024;
static constexpr int H  = 16;
static constexpr int HD = 64;
static constexpr int DS = 64;
static constexpr int B  = 2;
static constexpr int L  = 2048;
static constexpr int M  = B * L;   // 4096

// softmax scale * log2(e), folded into q at projection time (exp2-based
// softmax, no max subtraction: scores bounded far below exp2 overflow;
// masked scores (-1e30) give exp2 -> 0 exactly).
static constexpr float QSCALE = 0.18033688011112042f; // 0.125 * log2(e)

DEV unsigned short f2bf(float f) {
  union { float f; unsigned u; } x; x.f = f;
  unsigned r = (x.u + 0x7FFFu + ((x.u >> 16) & 1u)) >> 16;
  return (unsigned short)r;
}

DEV unsigned pack2bf(float a, float b) {
  return (unsigned)f2bf(a) | ((unsigned)f2bf(b) << 16);
}

// truncation pack (P only: truncation bias cancels between Sum(p*v) and Sum(p))
// single v_perm_b32: bytes [ua.b2, ua.b3, ub.b2, ub.b3]
DEV unsigned pack2bf_trunc(float a, float b) {
  union { float f; unsigned u; } ua{a}, ub{b};
  return __builtin_amdgcn_perm(ub.u, ua.u, 0x07060302u);
}

// async global->LDS, 16B per lane; LDS dest = wave-uniform base + 16*lane.
DEV void gload_lds16(const void* g, void* l) {
  __builtin_amdgcn_global_load_lds(
      (const __attribute__((address_space(1))) unsigned int*)g,
      (__attribute__((address_space(3))) unsigned int*)l, 16, 0, 0);
}

// ---------------- merged preprocessing ----------------
// blocks [0,1024): W transpose+bf16 (vectorized: float4 reads, ushort4
// transposed stores); [1024,3072): x->bf16; [3072,3088): sq/sk
__global__ __launch_bounds__(256) void prep_kernel(
    const float* __restrict__ Wq, const float* __restrict__ Wk,
    const float* __restrict__ Wv, const float* __restrict__ Wo,
    const float* __restrict__ x, const float* __restrict__ subj,
    const float* __restrict__ Wsq, const float* __restrict__ bsq,
    const float* __restrict__ Wsk, const float* __restrict__ bsk,
    unsigned short* __restrict__ WT4, unsigned short* __restrict__ xb,
    float* __restrict__ sq, float* __restrict__ sk) {
  __shared__ float tile[64][65];
  const int blk = blockIdx.x, t = threadIdx.x;
  if (blk < 1024) {
    const int z = blk >> 8, idx = blk & 255;
    const float* W = z == 0 ? Wq : z == 1 ? Wk : z == 2 ? Wv : Wo;
    unsigned short* dst = WT4 + (size_t)z * D * D;
    const int n0 = (idx & 15) * 64, k0 = (idx >> 4) * 64;
    const int c4 = (t & 15) * 4;   // 4-col group
    const int r16 = t >> 4;        // 0..15
#pragma unroll
    for (int rr = 0; rr < 4; ++rr) {
      int row = r16 + rr * 16;
      float4 v = *(const float4*)&W[(size_t)(k0 + row) * D + n0 + c4];
      tile[row][c4 + 0] = v.x;
      tile[row][c4 + 1] = v.y;
      tile[row][c4 + 2] = v.z;
      tile[row][c4 + 3] = v.w;
    }
    __syncthreads();
#pragma unroll
    for (int rr = 0; rr < 4; ++rr) {
      int nrow = r16 + rr * 16;
      ushort4 u;
      u.x = f2bf(tile[c4 + 0][nrow]);
      u.y = f2bf(tile[c4 + 1][nrow]);
      u.z = f2bf(tile[c4 + 2][nrow]);
      u.w = f2bf(tile[c4 + 3][nrow]);
      *(ushort4*)&dst[(size_t)(n0 + nrow) * D + k0 + c4] = u;
    }
  } else if (blk < 3072) {
    size_t g = (size_t)(blk - 1024) * 256 + t;
    const float4* xf = (const float4*)x;
    float4 a = xf[2 * g], b = xf[2 * g + 1];
    union { unsigned short s[8]; uint4 v; } o;
    o.s[0] = f2bf(a.x); o.s[1] = f2bf(a.y); o.s[2] = f2bf(a.z); o.s[3] = f2bf(a.w);
    o.s[4] = f2bf(b.x); o.s[5] = f2bf(b.y); o.s[6] = f2bf(b.z); o.s[7] = f2bf(b.w);
    ((uint4*)xb)[g] = o.v;
  } else {
    int g = (blk - 3072) * 256 + t;  // [0, 4096)
    int ty = g >> 11, b = (g >> 10) & 1, n = g & 1023;
    const float* W = ty ? Wsk : Wsq;
    const float* bias = ty ? bsk : bsq;
    float s = bias[n];
#pragma unroll 8
    for (int d = 0; d < DS; ++d) s += subj[b * DS + d] * W[d * D + n];
    (ty ? sk : sq)[b * D + n] = s;
  }
}

// ---------------- fused QKV projection GEMM (z-FUSED, BK=64 dbuf) -------
// One block computes q, k AND v for a 128(m) x 64(n=one head) tile: the
// shared A-operand (xb) is staged ONCE per K-step for 48 MFMAs (3 z x 16).
// Grid 512 = exactly 1 dispatch round. Per buf: As 16 KB + 3x Bs 8 KB =
// 40 KB; dbuf 80 KB -> 2 blocks/CU. 2D XCD chunk (8m x 8n per XCD).
// Three sequential epilogues (q, k: bias+coalesced; v: fused transpose).
__global__ __launch_bounds__(256) void proj_kernel(
    const unsigned short* __restrict__ xb, const unsigned short* __restrict__ WT3,
    const float* __restrict__ sq, const float* __restrict__ sk,
    unsigned short* __restrict__ qk, unsigned short* __restrict__ vT) {
  __shared__ __align__(16) unsigned short smem[40960];  // 80 KB: 2 bufs x 40 KB
  const int lin = blockIdx.x + 8 * blockIdx.y;     // 0..511
  const int x8 = lin & 7, c = lin >> 3;            // XCD, chunk idx 0..63
  const int mt = (x8 & 3) * 8 + (c >> 3);          // m-tile 0..31
  const int nt = (x8 >> 2) * 8 + (c & 7);          // n-tile (= head) 0..15
  const int m0 = mt * 128, n0 = nt * 64;
  const int t = threadIdx.x, l = t & 63, w = t >> 6;
  const int lm = l & 15, lq = l >> 4;
  const int srow8 = t >> 3;
  const int fsw = ((t & 7) ^ ((t >> 3) & 7)) * 8;
  const int swm = lm & 7;

  auto stage = [&](int kt, int bsel) {
    const int kb = kt * 64;
    unsigned short* As = smem + bsel * 20480;
    unsigned short* Bs = As + 8192;
#pragma unroll
    for (int cc = 0; cc < 4; ++cc)
      gload_lds16(&xb[(size_t)(m0 + 32 * cc + srow8) * D + kb + fsw],
                  &As[(32 * cc + 8 * w) * 64]);
#pragma unroll
    for (int z = 0; z < 3; ++z)
#pragma unroll
      for (int cc = 0; cc < 2; ++cc)
        gload_lds16(&WT3[(size_t)z * D * D + (size_t)(n0 + 32 * cc + srow8) * D + kb + fsw],
                    &Bs[z * 4096 + (32 * cc + 8 * w) * 64]);
  };

  f32x4 acc[3][2][4] = {};
  stage(0, 0);
  __syncthreads();
  for (int kt = 0; kt < D / 64; ++kt) {
    const int cur = kt & 1;
    if (kt + 1 < D / 64) stage(kt + 1, cur ^ 1);
    const unsigned short* As = smem + cur * 20480;
    const unsigned short* Bs = As + 8192;
#pragma unroll
    for (int kk = 0; kk < 2; ++kk) {
      bf16x8 af[2];
#pragma unroll
      for (int i = 0; i < 2; ++i)
        af[i] = *(const bf16x8*)&As[(32 * w + 16 * i + lm) * 64 + ((kk * 4 + lq) ^ swm) * 8];
#pragma unroll
      for (int z = 0; z < 3; ++z)
#pragma unroll
        for (int j = 0; j < 4; ++j) {
          bf16x8 bfj = *(const bf16x8*)&Bs[z * 4096 + (16 * j + lm) * 64 + ((kk * 4 + lq) ^ swm) * 8];
#pragma unroll
          for (int i = 0; i < 2; ++i)
            acc[z][i][j] = __builtin_amdgcn_mfma_f32_16x16x32_bf16(af[i], bfj, acc[z][i][j], 0, 0, 0);
        }
    }
    __syncthreads();  // vmcnt(0): prefetch (issued pre-compute) has landed
  }

  const int bb = m0 >> 11;          // batch
  const int l0 = m0 & (L - 1);      // seq offset
  const int h0 = nt;                // head (n0 = 64*nt)

  // ---- q/k epilogues: bias + QSCALE, stride-72 staging, coalesced stores
#pragma unroll
  for (int z = 0; z < 2; ++z) {
    const float* bias = z == 0 ? sq : sk;
    const float post = z == 0 ? QSCALE : 1.0f;
    unsigned short* dst = qk + (size_t)z * M * D;
#pragma unroll
    for (int i = 0; i < 2; ++i)
#pragma unroll
      for (int j = 0; j < 4; ++j)
#pragma unroll
        for (int r = 0; r < 4; ++r) {
          int rr = 32 * w + 16 * i + 4 * lq + r;
          int cc = 16 * j + lm;
          float v = (acc[z][i][j][r] + bias[bb * D + n0 + cc]) * post;
          smem[rr * 72 + cc] = f2bf(v);
        }
    __syncthreads();
    const int row = t >> 1, half = t & 1;
    size_t dbase = ((size_t)(bb * H + h0) * L + l0 + row) * HD + half * 32;
#pragma unroll
    for (int cq = 0; cq < 4; ++cq) {
      uint4 u = *(const uint4*)&smem[row * 72 + half * 32 + cq * 8];
      *(uint4*)&dst[dbase + cq * 8] = u;
    }
    __syncthreads();   // all reads done before next epilogue overwrites
  }

  // ---- v epilogue: transpose through smem (stride 136) -> vT[bh][hd][l]
#pragma unroll
  for (int i = 0; i < 2; ++i)
#pragma unroll
    for (int j = 0; j < 4; ++j) {
      int cr = 16 * j + lm;                 // hd 0..63
      int rr = 32 * w + 16 * i + 4 * lq;    // l-row 0..124
      uint2 u;
      u.x = pack2bf(acc[2][i][j][0], acc[2][i][j][1]);
      u.y = pack2bf(acc[2][i][j][2], acc[2][i][j][3]);
      *(uint2*)&smem[cr * 136 + rr] = u;
    }
  __syncthreads();
  {
    const int cr = t >> 2, quarter = t & 3;   // hd row, 32-el quarter
    size_t dbase = ((size_t)(bb * H + h0) * HD + cr) * L + l0 + quarter * 32;
#pragma unroll
    for (int cq = 0; cq < 4; ++cq) {
      uint4 u = *(const uint4*)&smem[cr * 136 + quarter * 32 + cq * 8];
      *(uint4*)&vT[dbase + cq * 8] = u;
    }
  }
}

// ---------------- flash attention (BK=128, register P, dbuf) ----------
// grid 512 XCD-swizzled; block 512 = 8 waves. Wave-pair key-split:
// wave w owns q-rows 32*(w&3)..+31 and 64 keys (2 groups of 32) of each
// 128-key tile. PV uses full-width mfma_f32_16x16x32_bf16 over 32-key
// groups via the QK^T A-operand K-row REMAP (see krow0/krow1).
// Row-sums via ones-column MFMA (same truncated bf16 p-values as PV ->
// truncation bias cancels in the ratio). s_setprio(1) wraps MFMA clusters.
// Mask bytes are loaded BEFORE the prefetch DMAs so the ballot's vmcnt wait
// does not drain the prefetch (FIFO vmcnt: mask loads are the oldest).
// MEASURED BEST of six attn structures (r14: 45.7 us); the 64-row/4-wave
// variant (r15: 55.5 us) halves per-wave amortization -> +10 us VALU.
__global__ __launch_bounds__(512, 4) void attn_kernel(
    const unsigned short* __restrict__ q_hm, const unsigned short* __restrict__ k_hm,
    const unsigned short* __restrict__ vT, const unsigned char* __restrict__ mask,
    unsigned short* __restrict__ ctx) {
  __shared__ __align__(16) unsigned short smem[40960];  // 80 KB pool
  unsigned short* Qs  = smem;                // 128*64   (16 KB)
  unsigned short* Ksb = smem + 8192;         // 2*128*64 (32 KB) [buf][key][feat]
  unsigned short* Vtb = smem + 24576;        // 2*64*128 (32 KB) [buf][feat][key]
  const int bx = blockIdx.x;
  const int rest = bx >> 3;
  const int bhid = (bx & 7) + 8 * (rest >> 4);
  const int q0 = (rest & 15) * 128;
  const int h = bhid & 15, b = bhid >> 4;
  const size_t bh = (size_t)(b * H + h);
  const unsigned short* qp = q_hm + bh * L * HD;
  const unsigned short* kp = k_hm + bh * L * HD;
  const unsigned short* vp = vT + bh * HD * L;
  const int t = threadIdx.x, l = t & 63, w = t >> 6;
  const int wq = w & 3, wj = w >> 2;               // q-row group, key half
  const int lm = l & 15, lq = l >> 4;
  const int fsw = ((t & 7) ^ ((t >> 3) & 7)) * 8;  // 8-chunk swizzle (64-wide rows)
  const int swm = lm & 7;
  const int srow = t >> 3;                         // 0..63
  const int vs = t & 15, vr = t >> 4;              // V staging: slot, row (0..31)
  const int vcsrc = ((vs & 8) | ((vs & 7) ^ (vr & 7))) * 8;  // 16-chunk swizzle
  // K=32 A-layout key-row remap (see header comment)
  const int krow0 = 8 * (lm >> 2) + 4 * ((lm >> 2) & 1) + (lm & 3);
  const int ks0 = krow0 & 7;
  const int krow1 = krow0 ^ 4;
  const int ks1 = ks0 ^ 4;
  const bf16x8 vones = {(short)0x3F80, (short)0x3F80, (short)0x3F80, (short)0x3F80,
                        (short)0x3F80, (short)0x3F80, (short)0x3F80, (short)0x3F80};

  // stage Q + first K/V tile (512 threads: 2 rounds each)
#pragma unroll
  for (int c = 0; c < 2; ++c) {
    gload_lds16(&qp[(size_t)(q0 + 64 * c + srow) * HD + fsw], &Qs[(64 * c + 8 * w) * 64]);
    gload_lds16(&kp[(size_t)(64 * c + srow) * HD + fsw], &Ksb[(64 * c + 8 * w) * 64]);
    gload_lds16(&vp[(size_t)(32 * c + vr) * L + vcsrc], &Vtb[(32 * c + 4 * w) * 128]);
  }
  __syncthreads();
  bf16x8 qf[2][2];
#pragma unroll
  for (int i = 0; i < 2; ++i)
#pragma unroll
    for (int kk = 0; kk < 2; ++kk)
      qf[i][kk] = *(const bf16x8*)&Qs[(wq * 32 + 16 * i + lm) * 64 + ((kk * 4 + lq) ^ swm) * 8];

  f32x4 ot[2][4] = {};   // O[qrow=32wq+16i+4lq+r][feat=16jf+lm], this wave's key-half
  f32x4 ot1[2] = {};     // row-sums (ones-column): lane rows 4lq+r (lm duplicated)

  for (int kt = 0; kt < L / 128; ++kt) {
    const int cur = kt & 1;
    const unsigned short* Kc = Ksb + cur * 8192;
    const unsigned short* Vc = Vtb + cur * 8192;
    // mask bytes FIRST (oldest vmcnt entries); each wave needs only its half
    unsigned char mby = mask[b * L + kt * 128 + 64 * wj + l];
    if (kt + 1 < L / 128) {
      const int nk0 = (kt + 1) * 128;
      unsigned short* Kd = Ksb + (cur ^ 1) * 8192;
      unsigned short* Vd = Vtb + (cur ^ 1) * 8192;
#pragma unroll
      for (int c = 0; c < 2; ++c) {
        gload_lds16(&kp[(size_t)(nk0 + 64 * c + srow) * HD + fsw], &Kd[(64 * c + 8 * w) * 64]);
        gload_lds16(&vp[(size_t)(32 * c + vr) * L + nk0 + vcsrc], &Vd[(32 * c + 4 * w) * 128]);
      }
    }
    unsigned long long mb = __ballot(mby != 0);

#pragma unroll
    for (int g = 0; g < 2; ++g) {
      const int gg = 2 * wj + g;            // 32-key group within 128-key tile
      const unsigned short* Kg = Kc + 32 * gg * 64;
      // remapped K fragments: rows krow0 (->j per lq parity) and krow1
      bf16x8 ka0 = *(const bf16x8*)&Kg[krow0 * 64 + ((0 + lq) ^ ks0) * 8];
      bf16x8 ka1 = *(const bf16x8*)&Kg[krow0 * 64 + ((4 + lq) ^ ks0) * 8];
      bf16x8 kb0 = *(const bf16x8*)&Kg[krow1 * 64 + ((0 + lq) ^ ks1) * 8];
      bf16x8 kb1 = *(const bf16x8*)&Kg[krow1 * 64 + ((4 + lq) ^ ks1) * 8];
      f32x4 stA[2], stB[2];
      __builtin_amdgcn_s_setprio(1);
#pragma unroll
      for (int i = 0; i < 2; ++i) {
        f32x4 a = {};
        a = __builtin_amdgcn_mfma_f32_16x16x32_bf16(ka0, qf[i][0], a, 0, 0, 0);
        a = __builtin_amdgcn_mfma_f32_16x16x32_bf16(ka1, qf[i][1], a, 0, 0, 0);
        stA[i] = a;
        f32x4 bq = {};
        bq = __builtin_amdgcn_mfma_f32_16x16x32_bf16(kb0, qf[i][0], bq, 0, 0, 0);
        bq = __builtin_amdgcn_mfma_f32_16x16x32_bf16(kb1, qf[i][1], bq, 0, 0, 0);
        stB[i] = bq;
      }
      __builtin_amdgcn_s_setprio(0);
      if (mb) {  // wave-uniform; all-false mask skips this
        // stA lane keys: 32g + 8lq + 4(lq&1) + r; stB: ^4
        const int shA = 32 * g + 8 * lq + 4 * (lq & 1);
        unsigned bitsA = (unsigned)(mb >> shA);
        unsigned bitsB = (unsigned)(mb >> (shA ^ 4));
#pragma unroll
        for (int i = 0; i < 2; ++i)
#pragma unroll
          for (int r = 0; r < 4; ++r) {
            if ((bitsA >> r) & 1u) stA[i][r] = -1e30f;
            if ((bitsB >> r) & 1u) stB[i][r] = -1e30f;
          }
      }
      // p = exp2(s); build K=32 A-fragment (lq parity selects quad order)
      union { uint4 q; bf16x8 v; } pa[2];
      const bool sw = (lq & 1) != 0;
#pragma unroll
      for (int i = 0; i < 2; ++i) {
        float eA[4], eB[4];
#pragma unroll
        for (int r = 0; r < 4; ++r) {
          eA[r] = __builtin_amdgcn_exp2f(stA[i][r]);
          eB[r] = __builtin_amdgcn_exp2f(stB[i][r]);
        }
        unsigned a01 = pack2bf_trunc(eA[0], eA[1]);
        unsigned a23 = pack2bf_trunc(eA[2], eA[3]);
        unsigned b01 = pack2bf_trunc(eB[0], eB[1]);
        unsigned b23 = pack2bf_trunc(eB[2], eB[3]);
        pa[i].q.x = sw ? b01 : a01;
        pa[i].q.y = sw ? b23 : a23;
        pa[i].q.z = sw ? a01 : b01;
        pa[i].q.w = sw ? a23 : b23;
      }
      // O += P@V for this 32-key group (b128 V^T reads, K=32 MFMA);
      // ones-column MFMA accumulates row-sums into ot1 (C-layout rows).
      const int kc = 4 * gg + lq;                    // 8-key chunk index
      const int slot = (kc & 8) | ((kc & 7) ^ swm);
      __builtin_amdgcn_s_setprio(1);
#pragma unroll
      for (int jf = 0; jf < 4; ++jf) {
        bf16x8 vb = *(const bf16x8*)&Vc[(16 * jf + lm) * 128 + slot * 8];
#pragma unroll
        for (int i = 0; i < 2; ++i)
          ot[i][jf] = __builtin_amdgcn_mfma_f32_16x16x32_bf16(pa[i].v, vb, ot[i][jf], 0, 0, 0);
      }
#pragma unroll
      for (int i = 0; i < 2; ++i)
        ot1[i] = __builtin_amdgcn_mfma_f32_16x16x32_bf16(pa[i].v, vones, ot1[i], 0, 0, 0);
      __builtin_amdgcn_s_setprio(0);
    }
    __syncthreads();
  }

  // ---- epilogue: combine wave-pair partials, normalize, store ----
  // All K/V/Q LDS is dead past the final loop barrier; carve scratch:
  float* Obuf = (float*)smem;                 // [64 cols][stride 132] f32, 33.8 KB
  unsigned short* Es = smem + 20480;          // byte 40960; stride-72 rows, 18.4 KB
  float* Sred = (float*)(smem + 35840);       // byte 71680; 8*32 floats

  // publish C-layout row sums (rows 32wq+16i+4lq+r); lm lanes duplicate
  if (lm == 0) {
#pragma unroll
    for (int i = 0; i < 2; ++i)
#pragma unroll
      for (int r = 0; r < 4; ++r)
        Sred[w * 32 + 16 * i + 4 * lq + r] = ot1[i][r];
  }
  if (wj) {
    // upper waves park raw O partials (col-major, r contiguous -> f32x4)
#pragma unroll
    for (int i = 0; i < 2; ++i)
#pragma unroll
      for (int jf = 0; jf < 4; ++jf)
        *(f32x4*)&Obuf[(16 * jf + lm) * 132 + wq * 32 + 16 * i + 4 * lq] = ot[i][jf];
  }
  __syncthreads();
  if (!wj) {
    float rlq[2][4];
#pragma unroll
    for (int i = 0; i < 2; ++i)
#pragma unroll
      for (int r = 0; r < 4; ++r)
        rlq[i][r] = 1.0f / (ot1[i][r] + Sred[(w + 4) * 32 + 16 * i + 4 * lq + r]);
#pragma unroll
    for (int i = 0; i < 2; ++i)
#pragma unroll
      for (int jf = 0; jf < 4; ++jf) {
        f32x4 po = *(const f32x4*)&Obuf[(16 * jf + lm) * 132 + wq * 32 + 16 * i + 4 * lq];
        ot[i][jf] += po;
      }
    // O rows -> Es (stride 72) -> coalesced 16B stores.
    // Safe without barrier: each wave touches only its own 32 rows.
#pragma unroll
    for (int i = 0; i < 2; ++i)
#pragma unroll
      for (int jf = 0; jf < 4; ++jf)
#pragma unroll
        for (int r = 0; r < 4; ++r)
          Es[(wq * 32 + 16 * i + 4 * lq + r) * 72 + 16 * jf + lm] =
              f2bf(ot[i][jf][r] * rlq[i][r]);
    int row = l >> 1, half = l & 1;
    size_t obase = ((size_t)(b * L + q0 + wq * 32 + row)) * D + h * HD + half * 32;
#pragma unroll
    for (int c = 0; c < 4; ++c) {
      uint4 u = *(const uint4*)&Es[(wq * 32 + row) * 72 + half * 32 + c * 8];
      *(uint4*)&ctx[obase + c * 8] = u;
    }
  }
}

// ---------------- output projection GEMM (BK=64, 2-phase dbuf) ----------
// out = ctx@Wo + bo. XCD-chunked block swizzle (bijective: 512 = 8 x 64)
// + 2-phase gload_lds prefetch (grid 512 = exactly 2 blocks/CU).
__global__ __launch_bounds__(256) void outgemm_kernel(
    const unsigned short* __restrict__ ctx, const unsigned short* __restrict__ WoT,
    const float* __restrict__ bo, float* __restrict__ out) {
  __shared__ __align__(16) unsigned short smem[24576];  // 48 KB: 2x(As+Bs)
  const int lin = blockIdx.x + 8 * blockIdx.y;
  const int nlin = (lin & 7) * 64 + (lin >> 3);   // XCD chunk remap
  const int m0 = (nlin >> 3) * 64, n0 = (nlin & 7) * 128;
  const int t = threadIdx.x, l = t & 63, w = t >> 6;
  const int wm = w >> 1, wn = w & 1;
  const int lm = l & 15, lq = l >> 4;
  const int srow8 = t >> 3;
  const int fsw = ((t & 7) ^ ((t >> 3) & 7)) * 8;
  const int swm = lm & 7;

  auto stage = [&](int kt, int bsel) {
    const int kb = kt * 64;
    unsigned short* As = smem + bsel * 12288;
    unsigned short* Bs = As + 4096;
#pragma unroll
    for (int c = 0; c < 2; ++c)
      gload_lds16(&ctx[(size_t)(m0 + 32 * c + srow8) * D + kb + fsw],
                  &As[(32 * c + 8 * w) * 64]);
#pragma unroll
    for (int c = 0; c < 4; ++c)
      gload_lds16(&WoT[(size_t)(n0 + 32 * c + srow8) * D + kb + fsw],
                  &Bs[(32 * c + 8 * w) * 64]);
  };

  f32x4 acc[2][4] = {};
  stage(0, 0);
  __syncthreads();
  for (int kt = 0; kt < D / 64; ++kt) {
    const int cur = kt & 1;
    if (kt + 1 < D / 64) stage(kt + 1, cur ^ 1);
    const unsigned short* As = smem + cur * 12288;
    const unsigned short* Bs = As + 4096;
#pragma unroll
    for (int kk = 0; kk < 2; ++kk) {
      bf16x8 af[2], bf[4];
#pragma unroll
      for (int i = 0; i < 2; ++i)
        af[i] = *(const bf16x8*)&As[(32 * wm + 16 * i + lm) * 64 + ((kk * 4 + lq) ^ swm) * 8];
#pragma unroll
      for (int j = 0; j < 4; ++j)
        bf[j] = *(const bf16x8*)&Bs[(64 * wn + 16 * j + lm) * 64 + ((kk * 4 + lq) ^ swm) * 8];
#pragma unroll
      for (int i = 0; i < 2; ++i)
#pragma unroll
        for (int j = 0; j < 4; ++j)
          acc[i][j] = __builtin_amdgcn_mfma_f32_16x16x32_bf16(af[i], bf[j], acc[i][j], 0, 0, 0);
    }
    __syncthreads();
  }
#pragma unroll
  for (int i = 0; i < 2; ++i)
#pragma unroll
    for (int j = 0; j < 4; ++j)
#pragma unroll
      for (int r = 0; r < 4; ++r) {
        int grow = m0 + 32 * wm + 16 * i + lq * 4 + r;
        int gcol = n0 + 64 * wn + 16 * j + lm;
        out[(size_t)grow * D + gcol] = acc[i][j][r] + bo[gcol];
      }
}

extern "C" void kernel_launch(void* const* d_in, const int* in_sizes, int n_in,
                              void* d_out, int out_size, void* d_ws, size_t ws_size,
                              hipStream_t stream) {
  const float* x    = (const float*)d_in[0];
  const float* subj = (const float*)d_in[1];
  const unsigned char* mask = (const unsigned char*)d_in[2];
  const float* Wq = (const float*)d_in[3];
  const float* Wk = (const float*)d_in[4];
  const float* Wv = (const float*)d_in[5];
  const float* Wo = (const float*)d_in[6];
  const float* bo = (const float*)d_in[7];
  const float* Wsq = (const float*)d_in[8];
  const float* bsq = (const float*)d_in[9];
  const float* Wsk = (const float*)d_in[10];
  const float* bsk = (const float*)d_in[11];
  float* out = (float*)d_out;
  char* ws = (char*)d_ws;

  // workspace layout (bytes)
  unsigned short* xb  = (unsigned short*)(ws);                    // 8 MB
  unsigned short* WT4 = (unsigned short*)(ws + (8ull  << 20));    // 8 MB
  unsigned short* qk  = (unsigned short*)(ws + (16ull << 20));    // 16 MB (q,k)
  unsigned short* ctx = (unsigned short*)(ws + (32ull << 20));    // 8 MB
  unsigned short* vT  = (unsigned short*)(ws + (40ull << 20));    // 8 MB
  float* sq = (float*)(ws + (48ull << 20));                       // 8 KB
  float* sk = sq + B * D;

  hipLaunchKernelGGL(prep_kernel, dim3(3088), dim3(256), 0, stream,
                     Wq, Wk, Wv, Wo, x, subj, Wsq, bsq, Wsk, bsk, WT4, xb, sq, sk);
  hipLaunchKernelGGL(proj_kernel, dim3(8, 64, 1), dim3(256), 0, stream,
                     xb, WT4, sq, sk, qk, vT);
  hipLaunchKernelGGL(attn_kernel, dim3(512), dim3(512), 0, stream,
                     qk, qk + (size_t)M * D, vT, mask, ctx);
  hipLaunchKernelGGL(outgemm_kernel, dim3(8, 64, 1), dim3(256), 0, stream, ctx,
                     WT4 + 3ull * D * D, bo, out);
}